// Round 7
// baseline (443.194 us; speedup 1.0000x reference)
//
#include <hip/hip_runtime.h>
#include <float.h>
#include <math.h>

#define D 128
#define PCHUNK 64    // nodes per pool block
#define NBUCK 256    // coarse buckets for CSR counting sort
#define BROWS 196    // rows per bucket (196*255 < 50000 <= 196*256)
#define BCAP 4096    // max edges per bucket (mean 3136, sigma ~56)
#define ACHUNK 3125  // edges per binA block

typedef _Float16 half8 __attribute__((ext_vector_type(8)));
typedef _Float16 half2v __attribute__((ext_vector_type(2)));
typedef float f32x4 __attribute__((ext_vector_type(4)));

// ---------- order-preserving float<->uint encode for atomicMax on f32 ----------
__device__ __forceinline__ unsigned encf(float x) {
    unsigned u = __float_as_uint(x);
    return (u & 0x80000000u) ? ~u : (u | 0x80000000u);
}
__device__ __forceinline__ float decf(unsigned e) {
    unsigned u = (e & 0x80000000u) ? (e & 0x7FFFFFFFu) : ~e;
    return __uint_as_float(u);
}

// ---------- CSR build, phase A: bin edges by dst/BROWS ----------
__global__ __launch_bounds__(256) void binA_kernel(const int* __restrict__ src,
                                                   const int* __restrict__ dst,
                                                   int* __restrict__ gcnt,
                                                   uint2* __restrict__ gpair, int ne) {
    __shared__ int lh[NBUCK], ssc[NBUCK], lstart[NBUCK], gbase[NBUCK], loff[NBUCK];
    __shared__ uint2 stage[ACHUNK + 8];
    int t = threadIdx.x;
    int e0 = blockIdx.x * ACHUNK;
    int e1 = min(e0 + ACHUNK, ne);
    lh[t] = 0;
    __syncthreads();
    for (int e = e0 + t; e < e1; e += 256) atomicAdd(&lh[dst[e] / BROWS], 1);
    __syncthreads();
    ssc[t] = lh[t];
    __syncthreads();
    for (int off = 1; off < NBUCK; off <<= 1) {
        int u = (t >= off) ? ssc[t - off] : 0;
        __syncthreads();
        ssc[t] += u;
        __syncthreads();
    }
    int st = ssc[t] - lh[t];
    lstart[t] = st;
    loff[t] = st;
    if (lh[t] > 0) gbase[t] = atomicAdd(&gcnt[t], lh[t]);
    __syncthreads();
    for (int e = e0 + t; e < e1; e += 256) {
        int s = src[e], d = dst[e];
        int pos = atomicAdd(&loff[d / BROWS], 1);
        stage[pos] = make_uint2((unsigned)s, (unsigned)d);
    }
    __syncthreads();
    int m = e1 - e0;
    for (int i = t; i < m; i += 256) {
        uint2 pr = stage[i];
        int b = (int)pr.y / BROWS;
        int gpos = b * BCAP + gbase[b] + (i - lstart[b]);
        if (gpos < (b + 1) * BCAP) gpair[gpos] = pr;  // clamp vs pathological overflow
    }
}

// ---------- scan bucket counts -> bucket starts; init outEnc ----------
__global__ __launch_bounds__(256) void scanB_kernel(const int* __restrict__ gcnt,
                                                    int* __restrict__ bstart,
                                                    unsigned* __restrict__ outEnc, int nout) {
    __shared__ int s[NBUCK], c[NBUCK];
    int t = threadIdx.x;
    for (int j = t; j < nout; j += 256) outEnc[j] = 0x007FFFFFu;  // encf(-inf)
    c[t] = gcnt[t];
    s[t] = c[t];
    __syncthreads();
    for (int off = 1; off < NBUCK; off <<= 1) {
        int u = (t >= off) ? s[t - off] : 0;
        __syncthreads();
        s[t] += u;
        __syncthreads();
    }
    bstart[t] = s[t] - c[t];
    if (t == NBUCK - 1) bstart[NBUCK] = s[NBUCK - 1];
}

// ---------- CSR build, phase B: per-bucket LDS histogram/scan/reorder ----------
__global__ __launch_bounds__(256) void binB_kernel(const uint2* __restrict__ gpair,
                                                   const int* __restrict__ gcnt,
                                                   const int* __restrict__ bstart,
                                                   int* __restrict__ rowptr,
                                                   float* __restrict__ disv,
                                                   int* __restrict__ csr, int n) {
    __shared__ int lh[256], ssc[256], lstart[256], loff[256];
    __shared__ int cstage[BCAP];
    int b = blockIdx.x, t = threadIdx.x;
    int m = min(gcnt[b], BCAP);
    int row0 = b * BROWS;
    int nrows = min(BROWS, n - row0);
    if (nrows <= 0) return;
    const uint2* mp = gpair + (size_t)b * BCAP;
    lh[t] = 0;
    __syncthreads();
    for (int i = t; i < m; i += 256) atomicAdd(&lh[(int)mp[i].y - row0], 1);
    __syncthreads();
    ssc[t] = lh[t];
    __syncthreads();
    for (int off = 1; off < 256; off <<= 1) {
        int u = (t >= off) ? ssc[t - off] : 0;
        __syncthreads();
        ssc[t] += u;
        __syncthreads();
    }
    int st = ssc[t] - lh[t];
    lstart[t] = st;
    loff[t] = st;
    __syncthreads();
    int bs = bstart[b];
    if (t <= nrows) rowptr[row0 + t] = bs + lstart[t];  // lstart[nrows] == m
    if (t < nrows) disv[row0 + t] = rsqrtf((float)lh[t] + 1.0f);
    for (int i = t; i < m; i += 256) {
        uint2 pr = mp[i];
        int pos = atomicAdd(&loff[(int)pr.y - row0], 1);
        cstage[pos] = (int)pr.x;
    }
    __syncthreads();
    for (int i = t; i < m; i += 256) csr[bs + i] = cstage[i];
}

// ---------- weight packing (all 3 weights in one launch) ----------
// Wp[((s*8 + t)*64 + lane)*8 + j] = W[s*32 + (lane>>4)*8 + j][t*16 + (lane&15)]
__global__ void pack3_kernel(const float* __restrict__ W1, const float* __restrict__ W2,
                             const float* __restrict__ W3, _Float16* __restrict__ Wp1,
                             _Float16* __restrict__ Wp2, _Float16* __restrict__ Wp3) {
    int gi = blockIdx.x * blockDim.x + threadIdx.x;  // 3*16384
    int w = gi >> 14, i = gi & 16383;
    const float* W = (w == 0) ? W1 : (w == 1) ? W2 : W3;
    _Float16* Wp = (w == 0) ? Wp1 : (w == 1) ? Wp2 : Wp3;
    int j = i & 7, l = (i >> 3) & 63, t = (i >> 9) & 7, s = (i >> 12) & 3;
    int k = s * 32 + ((l >> 4) << 3) + j;
    int c = t * 16 + (l & 15);
    Wp[i] = (_Float16)W[k * 128 + c];
}

// ---------- MFMA GEMM: Gh[i,:] = (fp16) dis[i] * (X[i,:] @ W) ----------
template <bool F32SRC>
__global__ __launch_bounds__(256) void gemm_mfma(const void* __restrict__ Xsrc,
                                                 const _Float16* __restrict__ Wp,
                                                 const float* __restrict__ disv,
                                                 _Float16* __restrict__ Gh,
                                                 int ntiles, int n) {
    __shared__ _Float16 Wl[16384];  // 32 KB
    int tid = threadIdx.x;
    {
        const uint4* s4 = (const uint4*)Wp;
        uint4* d4 = (uint4*)Wl;
#pragma unroll
        for (int i = 0; i < 8; i++) d4[tid + 256 * i] = s4[tid + 256 * i];
    }
    __syncthreads();
    int wave = tid >> 6, lane = tid & 63;
    int m = lane & 15, quad = lane >> 4;
    const half8* wfrag = (const half8*)Wl;
    const _Float16* Xh = (const _Float16*)Xsrc;
    const float* Xf = (const float*)Xsrc;

    for (int tile0 = blockIdx.x * 4; tile0 < ntiles; tile0 += gridDim.x * 4) {
        int tile = tile0 + wave;
        if (tile >= ntiles) break;
        int arow = tile * 16 + m;
        if (arow >= n) arow = n - 1;

        f32x4 acc[8];
#pragma unroll
        for (int t = 0; t < 8; t++) acc[t] = (f32x4){0.f, 0.f, 0.f, 0.f};

#pragma unroll
        for (int s = 0; s < 4; s++) {
            half8 a;
            if (F32SRC) {
                float4 lo = *(const float4*)(Xf + (size_t)arow * D + s * 32 + quad * 8);
                float4 hi = *(const float4*)(Xf + (size_t)arow * D + s * 32 + quad * 8 + 4);
                a[0] = (_Float16)lo.x; a[1] = (_Float16)lo.y; a[2] = (_Float16)lo.z; a[3] = (_Float16)lo.w;
                a[4] = (_Float16)hi.x; a[5] = (_Float16)hi.y; a[6] = (_Float16)hi.z; a[7] = (_Float16)hi.w;
            } else {
                a = *(const half8*)(Xh + (size_t)arow * D + s * 32 + quad * 8);
            }
#pragma unroll
            for (int t = 0; t < 8; t++) {
                half8 b = wfrag[(s * 8 + t) * 64 + lane];
                acc[t] = __builtin_amdgcn_mfma_f32_16x16x32_f16(a, b, acc[t], 0, 0, 0);
            }
        }
        int orow0 = tile * 16 + quad * 4;
        if (orow0 + 3 < n) {
            float d0 = disv[orow0], d1 = disv[orow0 + 1], d2 = disv[orow0 + 2], d3 = disv[orow0 + 3];
#pragma unroll
            for (int t = 0; t < 8; t++) {
                int col = t * 16 + m;
                Gh[(size_t)(orow0 + 0) * D + col] = (_Float16)(acc[t][0] * d0);
                Gh[(size_t)(orow0 + 1) * D + col] = (_Float16)(acc[t][1] * d1);
                Gh[(size_t)(orow0 + 2) * D + col] = (_Float16)(acc[t][2] * d2);
                Gh[(size_t)(orow0 + 3) * D + col] = (_Float16)(acc[t][3] * d3);
            }
        } else {
#pragma unroll
            for (int t = 0; t < 8; t++) {
                int col = t * 16 + m;
#pragma unroll
                for (int r = 0; r < 4; r++) {
                    int orow = orow0 + r;
                    if (orow < n) Gh[(size_t)orow * D + col] = (_Float16)(acc[t][r] * disv[orow]);
                }
            }
        }
    }
}

// ---------- pull aggregation, feature-dim quartered for L2 residency ----------
// Quarter q covers cols [32q, 32q+32) — per-pass gather working set 3.2 MB < 4 MiB
// XCD L2. Blocks are quarter-major (bq = blockIdx.x / nbq) so quarters are
// time-separated by dispatch order. Per wave: one node-quarter; 4 edge streams
// (sub = lane>>4) x 16 lanes x half2 -> 4 x 64 B segments per vmem instruction.
__global__ __launch_bounds__(256) void agg_f16(const _Float16* __restrict__ G,
                                               const int* __restrict__ rowptr,
                                               const int* __restrict__ csr,
                                               const float* __restrict__ disv,
                                               const float* __restrict__ bias,
                                               _Float16* __restrict__ Out,
                                               int n, int relu, int nbq) {
    int bq = blockIdx.x / nbq;           // quarter 0..3
    int bi = blockIdx.x - bq * nbq;
    int wave = threadIdx.x >> 6, lane = threadIdx.x & 63;
    int node = bi * 4 + wave;
    if (node >= n) return;
    int sub = lane >> 4, li = lane & 15;
    const _Float16* Gq = G + bq * 32;    // quarter column offset
    float ax, ay;
    if (sub == 0) {
        half2v sv = *(const half2v*)(Gq + (size_t)node * D + li * 2);  // self g[i]
        ax = (float)sv[0]; ay = (float)sv[1];
    } else {
        ax = 0.f; ay = 0.f;
    }
    int e = rowptr[node], end = rowptr[node + 1];
    for (; e + 16 <= end; e += 16) {
        int i0 = csr[e + sub], i1 = csr[e + 4 + sub];
        int i2 = csr[e + 8 + sub], i3 = csr[e + 12 + sub];
        half2v v0 = *(const half2v*)(Gq + (size_t)i0 * D + li * 2);
        half2v v1 = *(const half2v*)(Gq + (size_t)i1 * D + li * 2);
        half2v v2 = *(const half2v*)(Gq + (size_t)i2 * D + li * 2);
        half2v v3 = *(const half2v*)(Gq + (size_t)i3 * D + li * 2);
        ax += (((float)v0[0] + (float)v1[0]) + ((float)v2[0] + (float)v3[0]));
        ay += (((float)v0[1] + (float)v1[1]) + ((float)v2[1] + (float)v3[1]));
    }
    for (; e + 4 <= end; e += 4) {
        int i0 = csr[e + sub];
        half2v v0 = *(const half2v*)(Gq + (size_t)i0 * D + li * 2);
        ax += (float)v0[0]; ay += (float)v0[1];
    }
    int r = end - e;  // 0..3
    if (sub < r) {
        int i0 = csr[e + sub];
        half2v v0 = *(const half2v*)(Gq + (size_t)i0 * D + li * 2);
        ax += (float)v0[0]; ay += (float)v0[1];
    }
    // combine the 4 sub-streams
    ax += __shfl_xor(ax, 16); ax += __shfl_xor(ax, 32);
    ay += __shfl_xor(ay, 16); ay += __shfl_xor(ay, 32);
    if (sub == 0) {
        float dd = disv[node];
        int c = bq * 32 + li * 2;
        float ox = fmaf(dd, ax, bias[c]);
        float oy = fmaf(dd, ay, bias[c + 1]);
        if (relu) { ox = fmaxf(ox, 0.f); oy = fmaxf(oy, 0.f); }
        half2v o;
        o[0] = (_Float16)ox; o[1] = (_Float16)oy;
        *(half2v*)(Out + (size_t)node * D + c) = o;
    }
}

// ---------- pooling (reads fp16 H) ----------
__global__ __launch_bounds__(128) void pool_kernel(const _Float16* __restrict__ H,
                                                   const int* __restrict__ batch,
                                                   unsigned* __restrict__ outEnc, int n) {
    int d = threadIdx.x;
    int start = blockIdx.x * PCHUNK;
    if (start >= n) return;
    int end = min(start + PCHUNK, n);
    int curg = batch[start];
    float cur = -INFINITY;
    for (int i = start; i < end; i++) {
        float v = (float)H[(size_t)i * D + d];
        int g = batch[i];
        if (g != curg) { atomicMax(&outEnc[curg * D + d], encf(cur)); cur = v; curg = g; }
        else cur = fmaxf(cur, v);
    }
    atomicMax(&outEnc[curg * D + d], encf(cur));
}

__global__ void decode_kernel(const unsigned* __restrict__ outEnc, float* __restrict__ out, int n) {
    int i = blockIdx.x * blockDim.x + threadIdx.x;
    if (i < n) out[i] = decf(outEnc[i]);
}

// ---------- launcher ----------
extern "C" void kernel_launch(void* const* d_in, const int* in_sizes, int n_in,
                              void* d_out, int out_size, void* d_ws, size_t ws_size,
                              hipStream_t stream) {
    const float* x  = (const float*)d_in[0];
    const float* W1 = (const float*)d_in[1];
    const float* b1 = (const float*)d_in[2];
    const float* W2 = (const float*)d_in[3];
    const float* b2 = (const float*)d_in[4];
    const float* W3 = (const float*)d_in[5];
    const float* b3 = (const float*)d_in[6];
    const int* ei    = (const int*)d_in[7];
    const int* batch = (const int*)d_in[8];

    int n  = in_sizes[0] / D;   // 50000 nodes
    int ne = in_sizes[7] / 2;   // 800000 edges
    const int* src = ei;
    const int* dst = ei + ne;

    char* p = (char*)d_ws;
    auto alloc = [&](size_t bytes) -> void* {
        void* q = (void*)p;
        p += (bytes + 255) & ~(size_t)255;
        return q;
    };
    _Float16* Gh  = (_Float16*)alloc((size_t)n * D * 2);
    _Float16* Hh  = (_Float16*)alloc((size_t)n * D * 2);
    _Float16* Wp1 = (_Float16*)alloc((size_t)D * D * 2);
    _Float16* Wp2 = (_Float16*)alloc((size_t)D * D * 2);
    _Float16* Wp3 = (_Float16*)alloc((size_t)D * D * 2);
    int* gcnt     = (int*)alloc((size_t)NBUCK * 4);
    int* bstart   = (int*)alloc((size_t)(NBUCK + 1) * 4);
    uint2* gpair  = (uint2*)alloc((size_t)NBUCK * BCAP * 8);
    int* rowptr   = (int*)alloc((size_t)(n + 1) * 4);
    int* csr      = (int*)alloc((size_t)ne * 4);
    float* disv   = (float*)alloc((size_t)n * 4);
    unsigned* outEnc = (unsigned*)alloc((size_t)out_size * 4);

    hipMemsetAsync(gcnt, 0, (size_t)NBUCK * 4, stream);

    int nblocksA = (ne + ACHUNK - 1) / ACHUNK;  // 256
    binA_kernel<<<nblocksA, 256, 0, stream>>>(src, dst, gcnt, gpair, ne);
    scanB_kernel<<<1, 256, 0, stream>>>(gcnt, bstart, outEnc, out_size);
    binB_kernel<<<NBUCK, 256, 0, stream>>>(gpair, gcnt, bstart, rowptr, disv, csr, n);
    pack3_kernel<<<192, 256, 0, stream>>>(W1, W2, W3, Wp1, Wp2, Wp3);

    int ntiles = (n + 15) / 16;          // 3125
    int gemm_blocks = 512;               // persistent, grid-stride over tiles
    int nbq = (n + 3) / 4;               // blocks per quarter
    int agg_blocks = 4 * nbq;            // quarter-major block order

    // layer 1 (fp32 input converted in-register)
    gemm_mfma<true><<<gemm_blocks, 256, 0, stream>>>(x, Wp1, disv, Gh, ntiles, n);
    agg_f16<<<agg_blocks, 256, 0, stream>>>(Gh, rowptr, csr, disv, b1, Hh, n, 1, nbq);
    // layer 2
    gemm_mfma<false><<<gemm_blocks, 256, 0, stream>>>(Hh, Wp2, disv, Gh, ntiles, n);
    agg_f16<<<agg_blocks, 256, 0, stream>>>(Gh, rowptr, csr, disv, b2, Hh, n, 1, nbq);
    // layer 3
    gemm_mfma<false><<<gemm_blocks, 256, 0, stream>>>(Hh, Wp3, disv, Gh, ntiles, n);
    agg_f16<<<agg_blocks, 256, 0, stream>>>(Gh, rowptr, csr, disv, b3, Hh, n, 0, nbq);

    // global max pool
    pool_kernel<<<(n + PCHUNK - 1) / PCHUNK, 128, 0, stream>>>(Hh, batch, outEnc, n);
    decode_kernel<<<(out_size + 255) / 256, 256, 0, stream>>>(outEnc, (float*)d_out, out_size);
}

// Round 8
// 260.262 us; speedup vs baseline: 1.7029x; 1.7029x over previous
//
#include <hip/hip_runtime.h>
#include <float.h>
#include <math.h>

#define D 128
#define PCHUNK 64    // nodes per pool block
#define NBUCK 256    // coarse buckets for CSR counting sort
#define BROWS 196    // rows per bucket (196*255 < 50000 <= 196*256)
#define BCAP 4096    // max edges per bucket (mean 3136, sigma ~56)
#define ACHUNK 3125  // edges per binA block

typedef _Float16 half8 __attribute__((ext_vector_type(8)));
typedef _Float16 half2v __attribute__((ext_vector_type(2)));
typedef float f32x4 __attribute__((ext_vector_type(4)));

// ---------- order-preserving float<->uint encode for atomicMax on f32 ----------
__device__ __forceinline__ unsigned encf(float x) {
    unsigned u = __float_as_uint(x);
    return (u & 0x80000000u) ? ~u : (u | 0x80000000u);
}
__device__ __forceinline__ float decf(unsigned e) {
    unsigned u = (e & 0x80000000u) ? (e & 0x7FFFFFFFu) : ~e;
    return __uint_as_float(u);
}

// ---------- CSR build, phase A: bin edges by dst/BROWS ----------
__global__ __launch_bounds__(256) void binA_kernel(const int* __restrict__ src,
                                                   const int* __restrict__ dst,
                                                   int* __restrict__ gcnt,
                                                   uint2* __restrict__ gpair, int ne) {
    __shared__ int lh[NBUCK], ssc[NBUCK], lstart[NBUCK], gbase[NBUCK], loff[NBUCK];
    __shared__ uint2 stage[ACHUNK + 8];
    int t = threadIdx.x;
    int e0 = blockIdx.x * ACHUNK;
    int e1 = min(e0 + ACHUNK, ne);
    lh[t] = 0;
    __syncthreads();
    for (int e = e0 + t; e < e1; e += 256) atomicAdd(&lh[dst[e] / BROWS], 1);
    __syncthreads();
    ssc[t] = lh[t];
    __syncthreads();
    for (int off = 1; off < NBUCK; off <<= 1) {
        int u = (t >= off) ? ssc[t - off] : 0;
        __syncthreads();
        ssc[t] += u;
        __syncthreads();
    }
    int st = ssc[t] - lh[t];
    lstart[t] = st;
    loff[t] = st;
    if (lh[t] > 0) gbase[t] = atomicAdd(&gcnt[t], lh[t]);
    __syncthreads();
    for (int e = e0 + t; e < e1; e += 256) {
        int s = src[e], d = dst[e];
        int pos = atomicAdd(&loff[d / BROWS], 1);
        stage[pos] = make_uint2((unsigned)s, (unsigned)d);
    }
    __syncthreads();
    int m = e1 - e0;
    for (int i = t; i < m; i += 256) {
        uint2 pr = stage[i];
        int b = (int)pr.y / BROWS;
        int gpos = b * BCAP + gbase[b] + (i - lstart[b]);
        if (gpos < (b + 1) * BCAP) gpair[gpos] = pr;  // clamp vs pathological overflow
    }
}

// ---------- scan bucket counts -> bucket starts; init outEnc ----------
__global__ __launch_bounds__(256) void scanB_kernel(const int* __restrict__ gcnt,
                                                    int* __restrict__ bstart,
                                                    unsigned* __restrict__ outEnc, int nout) {
    __shared__ int s[NBUCK], c[NBUCK];
    int t = threadIdx.x;
    for (int j = t; j < nout; j += 256) outEnc[j] = 0x007FFFFFu;  // encf(-inf)
    c[t] = gcnt[t];
    s[t] = c[t];
    __syncthreads();
    for (int off = 1; off < NBUCK; off <<= 1) {
        int u = (t >= off) ? s[t - off] : 0;
        __syncthreads();
        s[t] += u;
        __syncthreads();
    }
    bstart[t] = s[t] - c[t];
    if (t == NBUCK - 1) bstart[NBUCK] = s[NBUCK - 1];
}

// ---------- CSR build, phase B: per-bucket LDS histogram/scan/reorder ----------
__global__ __launch_bounds__(256) void binB_kernel(const uint2* __restrict__ gpair,
                                                   const int* __restrict__ gcnt,
                                                   const int* __restrict__ bstart,
                                                   int* __restrict__ rowptr,
                                                   float* __restrict__ disv,
                                                   int* __restrict__ csr, int n) {
    __shared__ int lh[256], ssc[256], lstart[256], loff[256];
    __shared__ int cstage[BCAP];
    int b = blockIdx.x, t = threadIdx.x;
    int m = min(gcnt[b], BCAP);
    int row0 = b * BROWS;
    int nrows = min(BROWS, n - row0);
    if (nrows <= 0) return;
    const uint2* mp = gpair + (size_t)b * BCAP;
    lh[t] = 0;
    __syncthreads();
    for (int i = t; i < m; i += 256) atomicAdd(&lh[(int)mp[i].y - row0], 1);
    __syncthreads();
    ssc[t] = lh[t];
    __syncthreads();
    for (int off = 1; off < 256; off <<= 1) {
        int u = (t >= off) ? ssc[t - off] : 0;
        __syncthreads();
        ssc[t] += u;
        __syncthreads();
    }
    int st = ssc[t] - lh[t];
    lstart[t] = st;
    loff[t] = st;
    __syncthreads();
    int bs = bstart[b];
    if (t <= nrows) rowptr[row0 + t] = bs + lstart[t];  // lstart[nrows] == m
    if (t < nrows) disv[row0 + t] = rsqrtf((float)lh[t] + 1.0f);
    for (int i = t; i < m; i += 256) {
        uint2 pr = mp[i];
        int pos = atomicAdd(&loff[(int)pr.y - row0], 1);
        cstage[pos] = (int)pr.x;
    }
    __syncthreads();
    for (int i = t; i < m; i += 256) csr[bs + i] = cstage[i];
}

// ---------- weight packing (all 3 weights in one launch) ----------
// Wp[((s*8 + t)*64 + lane)*8 + j] = W[s*32 + (lane>>4)*8 + j][t*16 + (lane&15)]
__global__ void pack3_kernel(const float* __restrict__ W1, const float* __restrict__ W2,
                             const float* __restrict__ W3, _Float16* __restrict__ Wp1,
                             _Float16* __restrict__ Wp2, _Float16* __restrict__ Wp3) {
    int gi = blockIdx.x * blockDim.x + threadIdx.x;  // 3*16384
    int w = gi >> 14, i = gi & 16383;
    const float* W = (w == 0) ? W1 : (w == 1) ? W2 : W3;
    _Float16* Wp = (w == 0) ? Wp1 : (w == 1) ? Wp2 : Wp3;
    int j = i & 7, l = (i >> 3) & 63, t = (i >> 9) & 7, s = (i >> 12) & 3;
    int k = s * 32 + ((l >> 4) << 3) + j;
    int c = t * 16 + (l & 15);
    Wp[i] = (_Float16)W[k * 128 + c];
}

// ---------- MFMA GEMM: Gh[i,:] = (fp16) dis[i] * (X[i,:] @ W) ----------
// One block per 4 tiles (exactly; grid = ceil(ntiles/4) for load balance).
template <bool F32SRC>
__global__ __launch_bounds__(256) void gemm_mfma(const void* __restrict__ Xsrc,
                                                 const _Float16* __restrict__ Wp,
                                                 const float* __restrict__ disv,
                                                 _Float16* __restrict__ Gh,
                                                 int ntiles, int n) {
    __shared__ _Float16 Wl[16384];  // 32 KB
    int tid = threadIdx.x;
    {
        const uint4* s4 = (const uint4*)Wp;
        uint4* d4 = (uint4*)Wl;
#pragma unroll
        for (int i = 0; i < 8; i++) d4[tid + 256 * i] = s4[tid + 256 * i];
    }
    __syncthreads();
    int wave = tid >> 6, lane = tid & 63;
    int m = lane & 15, quad = lane >> 4;
    const half8* wfrag = (const half8*)Wl;
    const _Float16* Xh = (const _Float16*)Xsrc;
    const float* Xf = (const float*)Xsrc;

    int tile = blockIdx.x * 4 + wave;
    if (tile >= ntiles) return;
    int arow = tile * 16 + m;
    if (arow >= n) arow = n - 1;

    f32x4 acc[8];
#pragma unroll
    for (int t = 0; t < 8; t++) acc[t] = (f32x4){0.f, 0.f, 0.f, 0.f};

#pragma unroll
    for (int s = 0; s < 4; s++) {
        half8 a;
        if (F32SRC) {
            float4 lo = *(const float4*)(Xf + (size_t)arow * D + s * 32 + quad * 8);
            float4 hi = *(const float4*)(Xf + (size_t)arow * D + s * 32 + quad * 8 + 4);
            a[0] = (_Float16)lo.x; a[1] = (_Float16)lo.y; a[2] = (_Float16)lo.z; a[3] = (_Float16)lo.w;
            a[4] = (_Float16)hi.x; a[5] = (_Float16)hi.y; a[6] = (_Float16)hi.z; a[7] = (_Float16)hi.w;
        } else {
            a = *(const half8*)(Xh + (size_t)arow * D + s * 32 + quad * 8);
        }
#pragma unroll
        for (int t = 0; t < 8; t++) {
            half8 b = wfrag[(s * 8 + t) * 64 + lane];
            acc[t] = __builtin_amdgcn_mfma_f32_16x16x32_f16(a, b, acc[t], 0, 0, 0);
        }
    }
    int orow0 = tile * 16 + quad * 4;
    if (orow0 + 3 < n) {
        float d0 = disv[orow0], d1 = disv[orow0 + 1], d2 = disv[orow0 + 2], d3 = disv[orow0 + 3];
#pragma unroll
        for (int t = 0; t < 8; t++) {
            int col = t * 16 + m;
            Gh[(size_t)(orow0 + 0) * D + col] = (_Float16)(acc[t][0] * d0);
            Gh[(size_t)(orow0 + 1) * D + col] = (_Float16)(acc[t][1] * d1);
            Gh[(size_t)(orow0 + 2) * D + col] = (_Float16)(acc[t][2] * d2);
            Gh[(size_t)(orow0 + 3) * D + col] = (_Float16)(acc[t][3] * d3);
        }
    } else {
#pragma unroll
        for (int t = 0; t < 8; t++) {
            int col = t * 16 + m;
#pragma unroll
            for (int r = 0; r < 4; r++) {
                int orow = orow0 + r;
                if (orow < n) Gh[(size_t)orow * D + col] = (_Float16)(acc[t][r] * disv[orow]);
            }
        }
    }
}

// ---------- pull aggregation, 16B-per-lane gather ----------
// One wave per node. 16 lanes cover a 256B row; 4 edge streams (sub = lane>>4)
// gather 4 rows per vmem instruction; fp32 accumulate; shfl_xor(16,32) combine.
__global__ __launch_bounds__(256) void agg_f16(const _Float16* __restrict__ G,
                                               const int* __restrict__ rowptr,
                                               const int* __restrict__ csr,
                                               const float* __restrict__ disv,
                                               const float* __restrict__ bias,
                                               _Float16* __restrict__ Out, int n, int relu) {
    int wave = threadIdx.x >> 6, lane = threadIdx.x & 63;
    int node = blockIdx.x * 4 + wave;
    if (node >= n) return;
    int sub = lane >> 4, li = lane & 15;
    const half8* G8 = (const half8*)G;   // row = 16 half8
    float acc[8];
    if (sub == 0) {
        half8 sv = G8[(size_t)node * 16 + li];   // self contribution g[i]
#pragma unroll
        for (int j = 0; j < 8; j++) acc[j] = (float)sv[j];
    } else {
#pragma unroll
        for (int j = 0; j < 8; j++) acc[j] = 0.f;
    }
    int e = rowptr[node], end = rowptr[node + 1];
    for (; e + 16 <= end; e += 16) {
        int i0 = csr[e + sub], i1 = csr[e + 4 + sub];
        int i2 = csr[e + 8 + sub], i3 = csr[e + 12 + sub];
        half8 v0 = G8[(size_t)i0 * 16 + li];
        half8 v1 = G8[(size_t)i1 * 16 + li];
        half8 v2 = G8[(size_t)i2 * 16 + li];
        half8 v3 = G8[(size_t)i3 * 16 + li];
#pragma unroll
        for (int j = 0; j < 8; j++)
            acc[j] += ((float)v0[j] + (float)v1[j]) + ((float)v2[j] + (float)v3[j]);
    }
    for (; e + 4 <= end; e += 4) {
        int i0 = csr[e + sub];
        half8 v0 = G8[(size_t)i0 * 16 + li];
#pragma unroll
        for (int j = 0; j < 8; j++) acc[j] += (float)v0[j];
    }
    int r = end - e;  // 0..3
    if (sub < r) {
        int i0 = csr[e + sub];
        half8 v0 = G8[(size_t)i0 * 16 + li];
#pragma unroll
        for (int j = 0; j < 8; j++) acc[j] += (float)v0[j];
    }
    // combine the 4 sub-streams
#pragma unroll
    for (int j = 0; j < 8; j++) {
        acc[j] += __shfl_xor(acc[j], 16);
        acc[j] += __shfl_xor(acc[j], 32);
    }
    if (sub == 0) {
        float dd = disv[node];
        float4 b0 = *(const float4*)&bias[li * 8];
        float4 b1 = *(const float4*)&bias[li * 8 + 4];
        float o0 = fmaf(dd, acc[0], b0.x), o1 = fmaf(dd, acc[1], b0.y);
        float o2 = fmaf(dd, acc[2], b0.z), o3 = fmaf(dd, acc[3], b0.w);
        float o4 = fmaf(dd, acc[4], b1.x), o5 = fmaf(dd, acc[5], b1.y);
        float o6 = fmaf(dd, acc[6], b1.z), o7 = fmaf(dd, acc[7], b1.w);
        if (relu) {
            o0 = fmaxf(o0, 0.f); o1 = fmaxf(o1, 0.f); o2 = fmaxf(o2, 0.f); o3 = fmaxf(o3, 0.f);
            o4 = fmaxf(o4, 0.f); o5 = fmaxf(o5, 0.f); o6 = fmaxf(o6, 0.f); o7 = fmaxf(o7, 0.f);
        }
        half8 h;
        h[0] = (_Float16)o0; h[1] = (_Float16)o1; h[2] = (_Float16)o2; h[3] = (_Float16)o3;
        h[4] = (_Float16)o4; h[5] = (_Float16)o5; h[6] = (_Float16)o6; h[7] = (_Float16)o7;
        ((half8*)Out)[(size_t)node * 16 + li] = h;
    }
}

// ---------- pooling (reads fp16 H, half2 per thread, 2 sub-chunks per block) ----------
__global__ __launch_bounds__(128) void pool_kernel(const _Float16* __restrict__ H,
                                                   const int* __restrict__ batch,
                                                   unsigned* __restrict__ outEnc, int n) {
    int half = threadIdx.x >> 6;       // sub-chunk 0/1
    int li = threadIdx.x & 63;         // dim-pair index
    int start = blockIdx.x * PCHUNK + half * (PCHUNK / 2);
    if (start >= n) return;
    int end = min(start + PCHUNK / 2, n);
    int c = li * 2;
    int curg = batch[start];
    float cx = -INFINITY, cy = -INFINITY;
    for (int i = start; i < end; i++) {
        half2v v = *(const half2v*)(H + (size_t)i * D + c);
        float vx = (float)v[0], vy = (float)v[1];
        int g = batch[i];
        if (g != curg) {
            atomicMax(&outEnc[curg * D + c], encf(cx));
            atomicMax(&outEnc[curg * D + c + 1], encf(cy));
            cx = vx; cy = vy; curg = g;
        } else {
            cx = fmaxf(cx, vx); cy = fmaxf(cy, vy);
        }
    }
    atomicMax(&outEnc[curg * D + c], encf(cx));
    atomicMax(&outEnc[curg * D + c + 1], encf(cy));
}

__global__ void decode_kernel(const unsigned* __restrict__ outEnc, float* __restrict__ out, int n) {
    int i = blockIdx.x * blockDim.x + threadIdx.x;
    if (i < n) out[i] = decf(outEnc[i]);
}

// ---------- launcher ----------
extern "C" void kernel_launch(void* const* d_in, const int* in_sizes, int n_in,
                              void* d_out, int out_size, void* d_ws, size_t ws_size,
                              hipStream_t stream) {
    const float* x  = (const float*)d_in[0];
    const float* W1 = (const float*)d_in[1];
    const float* b1 = (const float*)d_in[2];
    const float* W2 = (const float*)d_in[3];
    const float* b2 = (const float*)d_in[4];
    const float* W3 = (const float*)d_in[5];
    const float* b3 = (const float*)d_in[6];
    const int* ei    = (const int*)d_in[7];
    const int* batch = (const int*)d_in[8];

    int n  = in_sizes[0] / D;   // 50000 nodes
    int ne = in_sizes[7] / 2;   // 800000 edges
    const int* src = ei;
    const int* dst = ei + ne;

    char* p = (char*)d_ws;
    auto alloc = [&](size_t bytes) -> void* {
        void* q = (void*)p;
        p += (bytes + 255) & ~(size_t)255;
        return q;
    };
    _Float16* Gh  = (_Float16*)alloc((size_t)n * D * 2);
    _Float16* Hh  = (_Float16*)alloc((size_t)n * D * 2);
    _Float16* Wp1 = (_Float16*)alloc((size_t)D * D * 2);
    _Float16* Wp2 = (_Float16*)alloc((size_t)D * D * 2);
    _Float16* Wp3 = (_Float16*)alloc((size_t)D * D * 2);
    int* gcnt     = (int*)alloc((size_t)NBUCK * 4);
    int* bstart   = (int*)alloc((size_t)(NBUCK + 1) * 4);
    uint2* gpair  = (uint2*)alloc((size_t)NBUCK * BCAP * 8);
    int* rowptr   = (int*)alloc((size_t)(n + 1) * 4);
    int* csr      = (int*)alloc((size_t)ne * 4);
    float* disv   = (float*)alloc((size_t)n * 4);
    unsigned* outEnc = (unsigned*)alloc((size_t)out_size * 4);

    hipMemsetAsync(gcnt, 0, (size_t)NBUCK * 4, stream);

    int nblocksA = (ne + ACHUNK - 1) / ACHUNK;  // 256
    binA_kernel<<<nblocksA, 256, 0, stream>>>(src, dst, gcnt, gpair, ne);
    scanB_kernel<<<1, 256, 0, stream>>>(gcnt, bstart, outEnc, out_size);
    binB_kernel<<<NBUCK, 256, 0, stream>>>(gpair, gcnt, bstart, rowptr, disv, csr, n);
    pack3_kernel<<<192, 256, 0, stream>>>(W1, W2, W3, Wp1, Wp2, Wp3);

    int ntiles = (n + 15) / 16;              // 3125
    int gemm_blocks = (ntiles + 3) / 4;      // 782 — exactly 4 tiles per block
    int agg_blocks  = (n + 3) / 4;

    // layer 1 (fp32 input converted in-register)
    gemm_mfma<true><<<gemm_blocks, 256, 0, stream>>>(x, Wp1, disv, Gh, ntiles, n);
    agg_f16<<<agg_blocks, 256, 0, stream>>>(Gh, rowptr, csr, disv, b1, Hh, n, 1);
    // layer 2
    gemm_mfma<false><<<gemm_blocks, 256, 0, stream>>>(Hh, Wp2, disv, Gh, ntiles, n);
    agg_f16<<<agg_blocks, 256, 0, stream>>>(Gh, rowptr, csr, disv, b2, Hh, n, 1);
    // layer 3
    gemm_mfma<false><<<gemm_blocks, 256, 0, stream>>>(Hh, Wp3, disv, Gh, ntiles, n);
    agg_f16<<<agg_blocks, 256, 0, stream>>>(Gh, rowptr, csr, disv, b3, Hh, n, 0);

    // global max pool
    pool_kernel<<<(n + PCHUNK - 1) / PCHUNK, 128, 0, stream>>>(Hh, batch, outEnc, n);
    decode_kernel<<<(out_size + 255) / 256, 256, 0, stream>>>(outEnc, (float*)d_out, out_size);
}

// Round 9
// 256.904 us; speedup vs baseline: 1.7251x; 1.0131x over previous
//
#include <hip/hip_runtime.h>
#include <float.h>
#include <math.h>

#define D 128
#define PCHUNK 64    // nodes per pool block
#define NBUCK 256    // coarse buckets for CSR counting sort
#define BROWS 196    // rows per bucket (196*255 < 50000 <= 196*256)
#define BCAP 4096    // max edges per bucket (mean 3136, sigma ~56)
#define ACHUNK 3125  // edges per binA block

typedef _Float16 half8 __attribute__((ext_vector_type(8)));
typedef _Float16 half2v __attribute__((ext_vector_type(2)));
typedef float f32x4 __attribute__((ext_vector_type(4)));

// ---------- order-preserving float<->uint encode for atomicMax on f32 ----------
__device__ __forceinline__ unsigned encf(float x) {
    unsigned u = __float_as_uint(x);
    return (u & 0x80000000u) ? ~u : (u | 0x80000000u);
}
__device__ __forceinline__ float decf(unsigned e) {
    unsigned u = (e & 0x80000000u) ? (e & 0x7FFFFFFFu) : ~e;
    return __uint_as_float(u);
}

// ---------- CSR build, phase A: bin edges by dst/BROWS ----------
__global__ __launch_bounds__(256) void binA_kernel(const int* __restrict__ src,
                                                   const int* __restrict__ dst,
                                                   int* __restrict__ gcnt,
                                                   uint2* __restrict__ gpair, int ne) {
    __shared__ int lh[NBUCK], ssc[NBUCK], lstart[NBUCK], gbase[NBUCK], loff[NBUCK];
    __shared__ uint2 stage[ACHUNK + 8];
    int t = threadIdx.x;
    int e0 = blockIdx.x * ACHUNK;
    int e1 = min(e0 + ACHUNK, ne);
    lh[t] = 0;
    __syncthreads();
    for (int e = e0 + t; e < e1; e += 256) atomicAdd(&lh[dst[e] / BROWS], 1);
    __syncthreads();
    ssc[t] = lh[t];
    __syncthreads();
    for (int off = 1; off < NBUCK; off <<= 1) {
        int u = (t >= off) ? ssc[t - off] : 0;
        __syncthreads();
        ssc[t] += u;
        __syncthreads();
    }
    int st = ssc[t] - lh[t];
    lstart[t] = st;
    loff[t] = st;
    if (lh[t] > 0) gbase[t] = atomicAdd(&gcnt[t], lh[t]);
    __syncthreads();
    for (int e = e0 + t; e < e1; e += 256) {
        int s = src[e], d = dst[e];
        int pos = atomicAdd(&loff[d / BROWS], 1);
        stage[pos] = make_uint2((unsigned)s, (unsigned)d);
    }
    __syncthreads();
    int m = e1 - e0;
    for (int i = t; i < m; i += 256) {
        uint2 pr = stage[i];
        int b = (int)pr.y / BROWS;
        int gpos = b * BCAP + gbase[b] + (i - lstart[b]);
        if (gpos < (b + 1) * BCAP) gpair[gpos] = pr;  // clamp vs pathological overflow
    }
}

// ---------- CSR build, phase B: per-bucket LDS histogram/scan/reorder ----------
// Also self-computes the bucket start (exclusive scan of gcnt) — no scanB kernel.
__global__ __launch_bounds__(256) void binB_kernel(const uint2* __restrict__ gpair,
                                                   const int* __restrict__ gcnt,
                                                   int* __restrict__ rowptr,
                                                   float* __restrict__ disv,
                                                   int* __restrict__ csr, int n) {
    __shared__ int lh[256], ssc[256], lstart[256], loff[256];
    __shared__ int gsc[NBUCK];
    __shared__ int cstage[BCAP];
    int b = blockIdx.x, t = threadIdx.x;
    int myc = gcnt[t];
    gsc[t] = myc;
    __syncthreads();
    for (int off = 1; off < NBUCK; off <<= 1) {
        int u = (t >= off) ? gsc[t - off] : 0;
        __syncthreads();
        gsc[t] += u;
        __syncthreads();
    }
    int bs = gsc[b] - gcnt[b];          // exclusive prefix for this bucket
    int m = min(gcnt[b], BCAP);
    int row0 = b * BROWS;
    int nrows = min(BROWS, n - row0);
    if (nrows <= 0) return;
    const uint2* mp = gpair + (size_t)b * BCAP;
    lh[t] = 0;
    __syncthreads();
    for (int i = t; i < m; i += 256) atomicAdd(&lh[(int)mp[i].y - row0], 1);
    __syncthreads();
    ssc[t] = lh[t];
    __syncthreads();
    for (int off = 1; off < 256; off <<= 1) {
        int u = (t >= off) ? ssc[t - off] : 0;
        __syncthreads();
        ssc[t] += u;
        __syncthreads();
    }
    int st = ssc[t] - lh[t];
    lstart[t] = st;
    loff[t] = st;
    __syncthreads();
    if (t <= nrows) rowptr[row0 + t] = bs + lstart[t];  // lstart[nrows] == m
    if (t < nrows) disv[row0 + t] = rsqrtf((float)lh[t] + 1.0f);
    for (int i = t; i < m; i += 256) {
        uint2 pr = mp[i];
        int pos = atomicAdd(&loff[(int)pr.y - row0], 1);
        cstage[pos] = (int)pr.x;
    }
    __syncthreads();
    for (int i = t; i < m; i += 256) csr[bs + i] = cstage[i];
}

// ---------- weight packing (all 3 weights in one launch) + outEnc init ----------
// Wp[((s*8 + t)*64 + lane)*8 + j] = W[s*32 + (lane>>4)*8 + j][t*16 + (lane&15)]
__global__ void pack3_kernel(const float* __restrict__ W1, const float* __restrict__ W2,
                             const float* __restrict__ W3, _Float16* __restrict__ Wp1,
                             _Float16* __restrict__ Wp2, _Float16* __restrict__ Wp3,
                             unsigned* __restrict__ outEnc, int nout) {
    int gi = blockIdx.x * blockDim.x + threadIdx.x;  // 3*16384
    if (gi < nout) outEnc[gi] = 0x007FFFFFu;         // encf(-inf)
    int w = gi >> 14, i = gi & 16383;
    const float* W = (w == 0) ? W1 : (w == 1) ? W2 : W3;
    _Float16* Wp = (w == 0) ? Wp1 : (w == 1) ? Wp2 : Wp3;
    int j = i & 7, l = (i >> 3) & 63, t = (i >> 9) & 7, s = (i >> 12) & 3;
    int k = s * 32 + ((l >> 4) << 3) + j;
    int c = t * 16 + (l & 15);
    Wp[i] = (_Float16)W[k * 128 + c];
}

// ---------- MFMA GEMM: Gh[i,:] = (fp16) dis[i] * (X[i,:] @ W) ----------
// One block per 4 tiles (exactly; grid = ceil(ntiles/4) for load balance).
template <bool F32SRC>
__global__ __launch_bounds__(256) void gemm_mfma(const void* __restrict__ Xsrc,
                                                 const _Float16* __restrict__ Wp,
                                                 const float* __restrict__ disv,
                                                 _Float16* __restrict__ Gh,
                                                 int ntiles, int n) {
    __shared__ _Float16 Wl[16384];  // 32 KB
    int tid = threadIdx.x;
    {
        const uint4* s4 = (const uint4*)Wp;
        uint4* d4 = (uint4*)Wl;
#pragma unroll
        for (int i = 0; i < 8; i++) d4[tid + 256 * i] = s4[tid + 256 * i];
    }
    __syncthreads();
    int wave = tid >> 6, lane = tid & 63;
    int m = lane & 15, quad = lane >> 4;
    const half8* wfrag = (const half8*)Wl;
    const _Float16* Xh = (const _Float16*)Xsrc;
    const float* Xf = (const float*)Xsrc;

    int tile = blockIdx.x * 4 + wave;
    if (tile >= ntiles) return;
    int arow = tile * 16 + m;
    if (arow >= n) arow = n - 1;

    f32x4 acc[8];
#pragma unroll
    for (int t = 0; t < 8; t++) acc[t] = (f32x4){0.f, 0.f, 0.f, 0.f};

#pragma unroll
    for (int s = 0; s < 4; s++) {
        half8 a;
        if (F32SRC) {
            float4 lo = *(const float4*)(Xf + (size_t)arow * D + s * 32 + quad * 8);
            float4 hi = *(const float4*)(Xf + (size_t)arow * D + s * 32 + quad * 8 + 4);
            a[0] = (_Float16)lo.x; a[1] = (_Float16)lo.y; a[2] = (_Float16)lo.z; a[3] = (_Float16)lo.w;
            a[4] = (_Float16)hi.x; a[5] = (_Float16)hi.y; a[6] = (_Float16)hi.z; a[7] = (_Float16)hi.w;
        } else {
            a = *(const half8*)(Xh + (size_t)arow * D + s * 32 + quad * 8);
        }
#pragma unroll
        for (int t = 0; t < 8; t++) {
            half8 b = wfrag[(s * 8 + t) * 64 + lane];
            acc[t] = __builtin_amdgcn_mfma_f32_16x16x32_f16(a, b, acc[t], 0, 0, 0);
        }
    }
    int orow0 = tile * 16 + quad * 4;
    if (orow0 + 3 < n) {
        float d0 = disv[orow0], d1 = disv[orow0 + 1], d2 = disv[orow0 + 2], d3 = disv[orow0 + 3];
#pragma unroll
        for (int t = 0; t < 8; t++) {
            int col = t * 16 + m;
            Gh[(size_t)(orow0 + 0) * D + col] = (_Float16)(acc[t][0] * d0);
            Gh[(size_t)(orow0 + 1) * D + col] = (_Float16)(acc[t][1] * d1);
            Gh[(size_t)(orow0 + 2) * D + col] = (_Float16)(acc[t][2] * d2);
            Gh[(size_t)(orow0 + 3) * D + col] = (_Float16)(acc[t][3] * d3);
        }
    } else {
#pragma unroll
        for (int t = 0; t < 8; t++) {
            int col = t * 16 + m;
#pragma unroll
            for (int r = 0; r < 4; r++) {
                int orow = orow0 + r;
                if (orow < n) Gh[(size_t)orow * D + col] = (_Float16)(acc[t][r] * disv[orow]);
            }
        }
    }
}

// ---------- pull aggregation, 16B-per-lane gather ----------
// One wave per node. 16 lanes cover a 256B row; 4 edge streams (sub = lane>>4)
// gather 4 rows per vmem instruction; fp32 accumulate; shfl_xor(16,32) combine.
__global__ __launch_bounds__(256) void agg_f16(const _Float16* __restrict__ G,
                                               const int* __restrict__ rowptr,
                                               const int* __restrict__ csr,
                                               const float* __restrict__ disv,
                                               const float* __restrict__ bias,
                                               _Float16* __restrict__ Out, int n, int relu) {
    int wave = threadIdx.x >> 6, lane = threadIdx.x & 63;
    int node = blockIdx.x * 4 + wave;
    if (node >= n) return;
    int sub = lane >> 4, li = lane & 15;
    const half8* G8 = (const half8*)G;   // row = 16 half8
    float acc[8];
    if (sub == 0) {
        half8 sv = G8[(size_t)node * 16 + li];   // self contribution g[i]
#pragma unroll
        for (int j = 0; j < 8; j++) acc[j] = (float)sv[j];
    } else {
#pragma unroll
        for (int j = 0; j < 8; j++) acc[j] = 0.f;
    }
    int e = rowptr[node], end = rowptr[node + 1];
    for (; e + 16 <= end; e += 16) {
        int i0 = csr[e + sub], i1 = csr[e + 4 + sub];
        int i2 = csr[e + 8 + sub], i3 = csr[e + 12 + sub];
        half8 v0 = G8[(size_t)i0 * 16 + li];
        half8 v1 = G8[(size_t)i1 * 16 + li];
        half8 v2 = G8[(size_t)i2 * 16 + li];
        half8 v3 = G8[(size_t)i3 * 16 + li];
#pragma unroll
        for (int j = 0; j < 8; j++)
            acc[j] += ((float)v0[j] + (float)v1[j]) + ((float)v2[j] + (float)v3[j]);
    }
    for (; e + 4 <= end; e += 4) {
        int i0 = csr[e + sub];
        half8 v0 = G8[(size_t)i0 * 16 + li];
#pragma unroll
        for (int j = 0; j < 8; j++) acc[j] += (float)v0[j];
    }
    int r = end - e;  // 0..3
    if (sub < r) {
        int i0 = csr[e + sub];
        half8 v0 = G8[(size_t)i0 * 16 + li];
#pragma unroll
        for (int j = 0; j < 8; j++) acc[j] += (float)v0[j];
    }
    // combine the 4 sub-streams
#pragma unroll
    for (int j = 0; j < 8; j++) {
        acc[j] += __shfl_xor(acc[j], 16);
        acc[j] += __shfl_xor(acc[j], 32);
    }
    if (sub == 0) {
        float dd = disv[node];
        float4 b0 = *(const float4*)&bias[li * 8];
        float4 b1 = *(const float4*)&bias[li * 8 + 4];
        float o0 = fmaf(dd, acc[0], b0.x), o1 = fmaf(dd, acc[1], b0.y);
        float o2 = fmaf(dd, acc[2], b0.z), o3 = fmaf(dd, acc[3], b0.w);
        float o4 = fmaf(dd, acc[4], b1.x), o5 = fmaf(dd, acc[5], b1.y);
        float o6 = fmaf(dd, acc[6], b1.z), o7 = fmaf(dd, acc[7], b1.w);
        if (relu) {
            o0 = fmaxf(o0, 0.f); o1 = fmaxf(o1, 0.f); o2 = fmaxf(o2, 0.f); o3 = fmaxf(o3, 0.f);
            o4 = fmaxf(o4, 0.f); o5 = fmaxf(o5, 0.f); o6 = fmaxf(o6, 0.f); o7 = fmaxf(o7, 0.f);
        }
        half8 h;
        h[0] = (_Float16)o0; h[1] = (_Float16)o1; h[2] = (_Float16)o2; h[3] = (_Float16)o3;
        h[4] = (_Float16)o4; h[5] = (_Float16)o5; h[6] = (_Float16)o6; h[7] = (_Float16)o7;
        ((half8*)Out)[(size_t)node * 16 + li] = h;
    }
}

// ---------- pooling (reads fp16 H, half2 per thread, 2 sub-chunks per block) ----------
__global__ __launch_bounds__(128) void pool_kernel(const _Float16* __restrict__ H,
                                                   const int* __restrict__ batch,
                                                   unsigned* __restrict__ outEnc, int n) {
    int half = threadIdx.x >> 6;       // sub-chunk 0/1
    int li = threadIdx.x & 63;         // dim-pair index
    int start = blockIdx.x * PCHUNK + half * (PCHUNK / 2);
    if (start >= n) return;
    int end = min(start + PCHUNK / 2, n);
    int c = li * 2;
    int curg = batch[start];
    float cx = -INFINITY, cy = -INFINITY;
    for (int i = start; i < end; i++) {
        half2v v = *(const half2v*)(H + (size_t)i * D + c);
        float vx = (float)v[0], vy = (float)v[1];
        int g = batch[i];
        if (g != curg) {
            atomicMax(&outEnc[curg * D + c], encf(cx));
            atomicMax(&outEnc[curg * D + c + 1], encf(cy));
            cx = vx; cy = vy; curg = g;
        } else {
            cx = fmaxf(cx, vx); cy = fmaxf(cy, vy);
        }
    }
    atomicMax(&outEnc[curg * D + c], encf(cx));
    atomicMax(&outEnc[curg * D + c + 1], encf(cy));
}

__global__ void decode_kernel(const unsigned* __restrict__ outEnc, float* __restrict__ out, int n) {
    int i = blockIdx.x * blockDim.x + threadIdx.x;
    if (i < n) out[i] = decf(outEnc[i]);
}

// ---------- launcher ----------
extern "C" void kernel_launch(void* const* d_in, const int* in_sizes, int n_in,
                              void* d_out, int out_size, void* d_ws, size_t ws_size,
                              hipStream_t stream) {
    const float* x  = (const float*)d_in[0];
    const float* W1 = (const float*)d_in[1];
    const float* b1 = (const float*)d_in[2];
    const float* W2 = (const float*)d_in[3];
    const float* b2 = (const float*)d_in[4];
    const float* W3 = (const float*)d_in[5];
    const float* b3 = (const float*)d_in[6];
    const int* ei    = (const int*)d_in[7];
    const int* batch = (const int*)d_in[8];

    int n  = in_sizes[0] / D;   // 50000 nodes
    int ne = in_sizes[7] / 2;   // 800000 edges
    const int* src = ei;
    const int* dst = ei + ne;

    char* p = (char*)d_ws;
    auto alloc = [&](size_t bytes) -> void* {
        void* q = (void*)p;
        p += (bytes + 255) & ~(size_t)255;
        return q;
    };
    _Float16* Gh  = (_Float16*)alloc((size_t)n * D * 2);
    _Float16* Hh  = (_Float16*)alloc((size_t)n * D * 2);
    _Float16* Wp1 = (_Float16*)alloc((size_t)D * D * 2);
    _Float16* Wp2 = (_Float16*)alloc((size_t)D * D * 2);
    _Float16* Wp3 = (_Float16*)alloc((size_t)D * D * 2);
    int* gcnt     = (int*)alloc((size_t)NBUCK * 4);
    uint2* gpair  = (uint2*)alloc((size_t)NBUCK * BCAP * 8);
    int* rowptr   = (int*)alloc((size_t)(n + 1) * 4);
    int* csr      = (int*)alloc((size_t)ne * 4);
    float* disv   = (float*)alloc((size_t)n * 4);
    unsigned* outEnc = (unsigned*)alloc((size_t)out_size * 4);

    hipMemsetAsync(gcnt, 0, (size_t)NBUCK * 4, stream);

    int nblocksA = (ne + ACHUNK - 1) / ACHUNK;  // 256
    binA_kernel<<<nblocksA, 256, 0, stream>>>(src, dst, gcnt, gpair, ne);
    binB_kernel<<<NBUCK, 256, 0, stream>>>(gpair, gcnt, rowptr, disv, csr, n);
    pack3_kernel<<<192, 256, 0, stream>>>(W1, W2, W3, Wp1, Wp2, Wp3, outEnc, out_size);

    int ntiles = (n + 15) / 16;              // 3125
    int gemm_blocks = (ntiles + 3) / 4;      // 782 — exactly 4 tiles per block
    int agg_blocks  = (n + 3) / 4;

    // layer 1 (fp32 input converted in-register)
    gemm_mfma<true><<<gemm_blocks, 256, 0, stream>>>(x, Wp1, disv, Gh, ntiles, n);
    agg_f16<<<agg_blocks, 256, 0, stream>>>(Gh, rowptr, csr, disv, b1, Hh, n, 1);
    // layer 2
    gemm_mfma<false><<<gemm_blocks, 256, 0, stream>>>(Hh, Wp2, disv, Gh, ntiles, n);
    agg_f16<<<agg_blocks, 256, 0, stream>>>(Gh, rowptr, csr, disv, b2, Hh, n, 1);
    // layer 3
    gemm_mfma<false><<<gemm_blocks, 256, 0, stream>>>(Hh, Wp3, disv, Gh, ntiles, n);
    agg_f16<<<agg_blocks, 256, 0, stream>>>(Gh, rowptr, csr, disv, b3, Hh, n, 0);

    // global max pool
    pool_kernel<<<(n + PCHUNK - 1) / PCHUNK, 128, 0, stream>>>(Hh, batch, outEnc, n);
    decode_kernel<<<(out_size + 255) / 256, 256, 0, stream>>>(outEnc, (float*)d_out, out_size);
}